// Round 2
// baseline (117.018 us; speedup 1.0000x reference)
//
#include <hip/hip_runtime.h>
#include <math.h>

// WignerDRotation: out = Z(alpha) * J * Z(beta) * J * Z(gamma) * x, block-diagonal
// over irreps [0]*256 + [1]*256 + [2]*128 + [3]*64, DIM=2112, CH=32, N=1024.
// All copies of the same l share one d x d composite matrix M_l per batch row.
//
// Two-kernel plan: (1) build_M writes the per-batch 3x3/5x5/7x7 composite
// matrices to d_ws (1024 x 96 floats, L2-resident); (2) the streaming kernel
// (512 thr, __launch_bounds__(512,8) -> 8 waves/SIMD) loads M into LDS and
// does one full-BW nontemporal pass over the 554 MB in+out stream.

namespace {

typedef float f4 __attribute__((ext_vector_type(4)));

constexpr float SQ3_2 = 0.86602540378443864676f;  // sqrt(3)/2
constexpr float S6    = 0.61237243569579452455f;  // sqrt(6)/4
constexpr float S10   = 0.79056941504209483300f;  // sqrt(10)/4
constexpr float S15   = 0.96824583655185422129f;  // sqrt(15)/4

// J_l: real-SH matrix of the y<->z axis swap (Condon-Shortley phase, rows/cols
// ordered m = -l..l). J = J^T = J^-1.
template<int L> struct JM;
template<> struct JM<1> {
  static constexpr float v[3][3] = {
    { 0.f, -1.f, 0.f},
    {-1.f,  0.f, 0.f},
    { 0.f,  0.f, 1.f}};
};
template<> struct JM<2> {
  static constexpr float v[5][5] = {
    { 0.f, 0.f,  0.f,   -1.f,  0.f},
    { 0.f, 1.f,  0.f,    0.f,  0.f},
    { 0.f, 0.f, -0.5f,   0.f, -SQ3_2},
    {-1.f, 0.f,  0.f,    0.f,  0.f},
    { 0.f, 0.f, -SQ3_2,  0.f,  0.5f}};
};
template<> struct JM<3> {
  static constexpr float v[7][7] = {
    { 0.f, 0.f, 0.f, S10,  0.f,   -S6,  0.f},
    { 0.f, 1.f, 0.f, 0.f,  0.f,    0.f, 0.f},
    { 0.f, 0.f, 0.f, S6,   0.f,    S10, 0.f},
    { S10, 0.f, S6,  0.f,  0.f,    0.f, 0.f},
    { 0.f, 0.f, 0.f, 0.f, -0.25f,  0.f, -S15},
    {-S6,  0.f, S10, 0.f,  0.f,    0.f, 0.f},
    { 0.f, 0.f, 0.f, 0.f, -S15,    0.f, 0.25f}};
};

// Column q of M_l = Zalpha * J * Zbeta * J * Zgamma. Column-local: Z only mixes
// m <-> -m inside a column, so each lane computes one column independently.
template<int L>
__device__ inline void compute_M_col(int q, float al, float be, float ga, float* M) {
  constexpr int D = 2 * L + 1;
  const int mq = q - L;
  float sg, cg;
  sincosf((float)mq * ga, &sg, &cg);
  float v[D];
#pragma unroll
  for (int p = 0; p < D; ++p)
    v[p] = cg * JM<L>::v[p][q] + sg * JM<L>::v[p][(D - 1) - q];
  float c1, s1;
  sincosf(be, &s1, &c1);
  float cb[L + 1], sb[L + 1];
  cb[0] = 1.f; sb[0] = 0.f;
  cb[1] = c1;  sb[1] = s1;
#pragma unroll
  for (int k = 2; k <= L; ++k) {
    cb[k] = 2.f * c1 * cb[k - 1] - cb[k - 2];
    sb[k] = 2.f * c1 * sb[k - 1] - sb[k - 2];
  }
  float w[D];
#pragma unroll
  for (int p = 0; p < D; ++p) {
    const int mp = p - L;
    const int am = mp < 0 ? -mp : mp;
    const float c = cb[am];
    const float s = mp < 0 ? -sb[am] : sb[am];
    w[p] = c * v[p] - s * v[(D - 1) - p];
  }
  float u[D];
#pragma unroll
  for (int p = 0; p < D; ++p) {
    float acc = 0.f;
#pragma unroll
    for (int r = 0; r < D; ++r) acc = fmaf(JM<L>::v[p][r], w[r], acc);
    u[p] = acc;
  }
  sincosf(al, &s1, &c1);
  float ca[L + 1], sa[L + 1];
  ca[0] = 1.f; sa[0] = 0.f;
  ca[1] = c1;  sa[1] = s1;
#pragma unroll
  for (int k = 2; k <= L; ++k) {
    ca[k] = 2.f * c1 * ca[k - 1] - ca[k - 2];
    sa[k] = 2.f * c1 * sa[k - 1] - sa[k - 2];
  }
#pragma unroll
  for (int p = 0; p < D; ++p) {
    const int mp = p - L;
    const int am = mp < 0 ? -mp : mp;
    const float c = ca[am];
    const float s = mp < 0 ? -sa[am] : sa[am];
    M[p * D + q] = c * u[p] - s * u[(D - 1) - p];
  }
}

// ws layout per batch row n (96 floats): M3(7x7)@0..48, M2(5x5)@49..73, M1(3x3)@74..82.
__global__ __launch_bounds__(256) void build_M_kernel(
    const float* __restrict__ alpha, const float* __restrict__ beta,
    const float* __restrict__ gamma, float* __restrict__ ws, int n_batch) {
  const int t = threadIdx.x;
  const int n = blockIdx.x * 16 + (t >> 4);
  const int col = t & 15;
  if (n >= n_batch || col >= 15) return;
  const float al = alpha[n], be = beta[n], ga = gamma[n];
  float* w = ws + (size_t)n * 96;
  if (col < 7)       compute_M_col<3>(col,      al, be, ga, w);
  else if (col < 12) compute_M_col<2>(col - 7,  al, be, ga, w + 49);
  else               compute_M_col<1>(col - 12, al, be, ga, w + 74);
}

// One 8-lane group applies M (d x d, LDS broadcast) to one irrep copy:
// d rows x 32 channels, each lane owns 4 channels (one float4).
template<int D>
__device__ inline void apply_block(const f4* __restrict__ inN,
                                   f4* __restrict__ outN,
                                   const float* __restrict__ M, int off, int ch) {
  f4 v[D];
#pragma unroll
  for (int q = 0; q < D; ++q)
    v[q] = __builtin_nontemporal_load(&inN[(off + q) * 8 + ch]);
#pragma unroll
  for (int p = 0; p < D; ++p) {
    f4 a = M[p * D] * v[0];
#pragma unroll
    for (int q = 1; q < D; ++q) a += M[p * D + q] * v[q];  // contracts to v_fma
    __builtin_nontemporal_store(a, &outN[(off + p) * 8 + ch]);
  }
}

// Shared streaming body: 512 threads = 64 groups of 8 lanes; uniform l per iter.
__device__ inline void stream_body(const float* __restrict__ in,
                                   float* __restrict__ out,
                                   const float* __restrict__ M,  // LDS, 96 floats
                                   int n, int t) {
  const float* M3 = M;
  const float* M2 = M + 49;
  const float* M1 = M + 74;
  const size_t base = (size_t)n * (2112 * 8);  // f4 units
  const f4* inN = (const f4*)in + base;
  f4* outN = (f4*)out + base;
  const int g = t >> 3;   // group 0..63: one irrep copy per iteration
  const int ch = t & 7;

  // l=0 (rows 0..255): identity copy.
#pragma unroll
  for (int j = 0; j < 4; ++j) {
    const int r = 64 * j + g;
    __builtin_nontemporal_store(__builtin_nontemporal_load(&inN[r * 8 + ch]),
                                &outN[r * 8 + ch]);
  }
  // l=1: 256 copies, rows 256..1023
#pragma unroll
  for (int j = 0; j < 4; ++j)
    apply_block<3>(inN, outN, M1, 256 + 3 * (64 * j + g), ch);
  // l=2: 128 copies, rows 1024..1663
#pragma unroll
  for (int j = 0; j < 2; ++j)
    apply_block<5>(inN, outN, M2, 1024 + 5 * (64 * j + g), ch);
  // l=3: 64 copies, rows 1664..2111
  apply_block<7>(inN, outN, M3, 1664 + 7 * g, ch);
}

// Fast path: M precomputed in ws. 8 waves/SIMD occupancy (64-VGPR cap is safe:
// apply_block<7> peaks ~45 VGPRs; the spill-prone compute_M_col lives in
// build_M_kernel instead).
__global__ __launch_bounds__(512, 8) void wigner_stream_kernel(
    const float* __restrict__ in, const float* __restrict__ ws,
    float* __restrict__ out) {
  __shared__ float M[96];
  const int n = blockIdx.x;
  const int t = threadIdx.x;
  if (t < 83) M[t] = ws[(size_t)n * 96 + t];
  __syncthreads();
  stream_body(in, out, M, n, t);
}

// Fallback if ws is too small: compute M in-block (no VGPR cap requested).
__global__ __launch_bounds__(512) void wigner_fused_kernel(
    const float* __restrict__ in, const float* __restrict__ alpha,
    const float* __restrict__ beta, const float* __restrict__ gamma,
    float* __restrict__ out) {
  __shared__ float M[96];
  const int n = blockIdx.x;
  const int t = threadIdx.x;
  if (t < 15) {
    const float al = alpha[n], be = beta[n], ga = gamma[n];
    if (t < 7)       compute_M_col<3>(t,      al, be, ga, M);
    else if (t < 12) compute_M_col<2>(t - 7,  al, be, ga, M + 49);
    else             compute_M_col<1>(t - 12, al, be, ga, M + 74);
  }
  __syncthreads();
  stream_body(in, out, M, n, t);
}

}  // namespace

extern "C" void kernel_launch(void* const* d_in, const int* in_sizes, int n_in,
                              void* d_out, int out_size, void* d_ws, size_t ws_size,
                              hipStream_t stream) {
  const float* in    = (const float*)d_in[0];
  const float* alpha = (const float*)d_in[1];
  const float* beta  = (const float*)d_in[2];
  const float* gamma = (const float*)d_in[3];
  float* out = (float*)d_out;
  const int n_batch = in_sizes[1];  // 1024

  const size_t ws_needed = (size_t)n_batch * 96 * sizeof(float);
  if (ws_size >= ws_needed) {
    float* ws = (float*)d_ws;
    build_M_kernel<<<(n_batch + 15) / 16, 256, 0, stream>>>(alpha, beta, gamma,
                                                            ws, n_batch);
    wigner_stream_kernel<<<n_batch, 512, 0, stream>>>(in, ws, out);
  } else {
    wigner_fused_kernel<<<n_batch, 512, 0, stream>>>(in, alpha, beta, gamma, out);
  }
}